// Round 1
// baseline (268.769 us; speedup 1.0000x reference)
//
#include <hip/hip_runtime.h>

// KernelAggregation: per-sample mixed 3x3 SAME conv, implicit GEMM via bf16 MFMA.
// ws layout: [0, 2359296) = wmix bf16, fragment-major [32 b][9 tap][2 s][4 mt][64 lane][8 j];
//            [2359296, +8192) = bmix f32 [32][64].

#define DIM 64
#define BATCH 32
#define HH 128
#define WW 128
#define NK 4

typedef __attribute__((ext_vector_type(4))) float f32x4;
typedef __attribute__((ext_vector_type(8))) short bf16x8;
typedef __attribute__((ext_vector_type(8))) unsigned short ushort8;

static __device__ __forceinline__ unsigned short f2bf(float f) {
    union { float f; unsigned u; } v; v.f = f;
    unsigned r = v.u + 0x7fffu + ((v.u >> 16) & 1u);   // RNE, inputs finite
    return (unsigned short)(r >> 16);
}
static __device__ __forceinline__ unsigned pack2(float a, float b) {
    return (unsigned)f2bf(a) | ((unsigned)f2bf(b) << 16);
}

// One wave per (b, co): coalesced read of w[k][co][ci][kh][kw] (576 contiguous
// floats per k), mix over k in registers, LDS transpose (ci,tap)->(tap,ci),
// then scatter into the fragment-major wmix layout consumed by conv_mfma:
//   element (co, ci, tap) -> [tap][s=ci>>5][mt=co>>4][lane=((ci>>3)&3)<<4|(co&15)][j=ci&7]
__global__ __launch_bounds__(256) void mix_weights(
    const float* __restrict__ w, const float* __restrict__ att,
    unsigned short* __restrict__ wmix) {
    __shared__ float tr[4][576];
    int wave = threadIdx.x >> 6, lane = threadIdx.x & 63;
    int idx = blockIdx.x * 4 + wave;               // 2048 (b,co) pairs
    int b = idx >> 6, co = idx & 63;
    float a[NK];
    #pragma unroll
    for (int k = 0; k < NK; ++k) a[k] = att[b * NK + k];
    float s[9];
    #pragma unroll
    for (int t = 0; t < 9; ++t) s[t] = 0.f;
    #pragma unroll
    for (int k = 0; k < NK; ++k) {
        const float* wp = w + (size_t)(k * DIM + co) * 576;
        #pragma unroll
        for (int t = 0; t < 9; ++t)
            s[t] += a[k] * wp[t * 64 + lane];      // element e = t*64+lane = ci*9+tap
    }
    #pragma unroll
    for (int t = 0; t < 9; ++t) tr[wave][t * 64 + lane] = s[t];
    __syncthreads();
    // after transpose: lane holds (ci=lane, tap=t) of this (b,co)
    int mt = co >> 4;
    int lo = ((lane >> 3) & 3) * 16 + (co & 15);   // fragment lane
    int ss = lane >> 5;
    int jj = lane & 7;
    #pragma unroll
    for (int t = 0; t < 9; ++t) {
        float v = tr[wave][lane * 9 + t];
        wmix[(size_t)((((b * 9 + t) * 2 + ss) * 4 + mt) * 64 + lo) * 8 + jj] = f2bf(v);
    }
}

__global__ __launch_bounds__(256) void mix_bias(
    const float* __restrict__ bias, const float* __restrict__ att,
    float* __restrict__ bmix) {
    int idx = blockIdx.x * 256 + threadIdx.x;      // 2048
    if (idx >= BATCH * DIM) return;
    int b = idx >> 6, co = idx & 63;
    float s = 0.f;
    for (int k = 0; k < NK; ++k) s += att[b * NK + k] * bias[k * DIM + co];
    bmix[idx] = s;
}

// Block = (sample b, 4 output rows, 64 output cols). 4 waves; wave = one output
// row, tile M=64 co x N=64 cols, 9 taps x 2 K-steps of mfma_f32_16x16x32_bf16.
// Xs[r][c][ci] bf16, ci-group swizzled by (c>>1)&7 (reads 2-way=free).
// No Ws: A-fragments loaded fragment-major from global (L2-resident wmix) with
// 1-step register prefetch -> ONE barrier per block, no per-tap lockstep.
// LDS = 50,688 B -> 3 blocks/CU (12 waves).
__global__ __launch_bounds__(256, 3) void conv_mfma(
    const float* __restrict__ x, const unsigned short* __restrict__ wmix,
    const float* __restrict__ bmix, float* __restrict__ out) {

    __shared__ unsigned short Xs[6 * 66 * 64];     // 50,688 B

    int bid = blockIdx.x;
    bid = (bid & 7) * 256 + (bid >> 3);            // XCD-contiguous remap (2048 = 8*256)
    int b   = bid >> 6;
    int r6  = bid & 63;
    int h0  = (r6 >> 1) * 4;
    int w0  = (r6 & 1) * 64;

    int tid  = threadIdx.x;
    int wave = tid >> 6, lane = tid & 63;
    int l15  = lane & 15, q = lane >> 4;

    // ---- stage X: rows hin = h0-1 .. h0+4, cols w0..w0+63. Thread owns a
    // ci-pair (2p, 2p+1) at each col quad -> packed b32 LDS writes.
    #pragma unroll
    for (int half = 0; half < 2; ++half) {
        f32x4 xv[3][2][2];
        #pragma unroll
        for (int rr = 0; rr < 3; ++rr) {
            int r = half * 3 + rr;
            int hin = h0 - 1 + r;
            bool ok = (hin >= 0) && (hin < HH);    // wave-uniform
            #pragma unroll
            for (int it = 0; it < 2; ++it) {
                int slot = it * 256 + tid;
                int p = slot >> 4, c4 = slot & 15;
                f32x4 z = {0.f, 0.f, 0.f, 0.f};
                xv[rr][it][0] = ok ? *(const f32x4*)&x[(((size_t)b * DIM + 2 * p    ) * HH + hin) * WW + w0 + c4 * 4] : z;
                xv[rr][it][1] = ok ? *(const f32x4*)&x[(((size_t)b * DIM + 2 * p + 1) * HH + hin) * WW + w0 + c4 * 4] : z;
            }
        }
        #pragma unroll
        for (int rr = 0; rr < 3; ++rr) {
            int r = half * 3 + rr;
            #pragma unroll
            for (int it = 0; it < 2; ++it) {
                int slot = it * 256 + tid;
                int p = slot >> 4, c4 = slot & 15;
                #pragma unroll
                for (int j = 0; j < 4; ++j) {
                    int c = c4 * 4 + 1 + j;
                    int xi = (r * 66 + c) * 64 + (((p >> 2) ^ ((c >> 1) & 7)) << 3) + 2 * (p & 3);
                    *(unsigned*)&Xs[xi] = pack2(xv[rr][it][0][j], xv[rr][it][1][j]);
                }
            }
        }
    }
    // edge cols c=0 (win=w0-1) and c=65 (win=w0+64): 768 items, 3/thread
    #pragma unroll
    for (int e = 0; e < 3; ++e) {
        int item = e * 256 + tid;
        int edge = item >= 384;
        int jj = item - edge * 384;
        int ci = jj & 63, r = jj >> 6;
        int hin = h0 - 1 + r;
        int win = edge ? (w0 + 64) : (w0 - 1);
        float v = 0.f;
        if (hin >= 0 && hin < HH && win >= 0 && win < WW)
            v = x[(((size_t)b * DIM + ci) * HH + hin) * WW + win];
        int c = edge ? 65 : 0;
        Xs[(r * 66 + c) * 64 + (((ci >> 3) ^ ((c >> 1) & 7)) << 3) + (ci & 7)] = f2bf(v);
    }

    // ---- A-fragment prefetch from fragment-major wmix (lane-linear, 1 KB/wave-load)
    const unsigned short* wa = wmix + (size_t)b * 9 * 4096;   // 4096 elems per tap
    bf16x8 afp[4];
    #pragma unroll
    for (int mt = 0; mt < 4; ++mt)
        afp[mt] = *(const bf16x8*)&wa[(size_t)(mt * 64 + lane) * 8];

    f32x4 acc[4][4];
    f32x4 zero = {0.f, 0.f, 0.f, 0.f};
    #pragma unroll
    for (int mt = 0; mt < 4; ++mt)
        #pragma unroll
        for (int nt = 0; nt < 4; ++nt) acc[mt][nt] = zero;

    __syncthreads();                               // Xs visible — the only barrier

    #pragma unroll
    for (int tap = 0; tap < 9; ++tap) {
        int kh = tap / 3, kw = tap - kh * 3;       // compile-time (unrolled)
        int r = wave + kh;
        #pragma unroll
        for (int s = 0; s < 2; ++s) {
            int u = tap * 2 + s;
            bf16x8 afc[4];
            #pragma unroll
            for (int mt = 0; mt < 4; ++mt) afc[mt] = afp[mt];
            if (u < 17) {                          // prefetch next (tap,s) step
                #pragma unroll
                for (int mt = 0; mt < 4; ++mt)
                    afp[mt] = *(const bf16x8*)&wa[(size_t)(((u + 1) * 4 + mt) * 64 + lane) * 8];
            }
            int g = s * 4 + q;                     // k = s*32 + q*8 + j
            bf16x8 bfr[4];
            #pragma unroll
            for (int nt = 0; nt < 4; ++nt) {
                int c = nt * 16 + l15 + kw;        // B[k][n=lane&15]
                bfr[nt] = *(const bf16x8*)&Xs[(r * 66 + c) * 64 + ((g ^ ((c >> 1) & 7)) << 3)];
            }
            #pragma unroll
            for (int mt = 0; mt < 4; ++mt)
                #pragma unroll
                for (int nt = 0; nt < 4; ++nt)
                    acc[mt][nt] = __builtin_amdgcn_mfma_f32_16x16x32_bf16(
                        afc[mt], bfr[nt], acc[mt][nt], 0, 0, 0);
        }
    }

    // epilogue: C/D layout col=lane&15 (w), row=quad*4+reg (co)
    float biasr[4][4];
    #pragma unroll
    for (int mt = 0; mt < 4; ++mt)
        #pragma unroll
        for (int rg = 0; rg < 4; ++rg)
            biasr[mt][rg] = bmix[b * DIM + mt * 16 + q * 4 + rg];
    int h = h0 + wave;
    #pragma unroll
    for (int mt = 0; mt < 4; ++mt) {
        #pragma unroll
        for (int nt = 0; nt < 4; ++nt) {
            int wcol = w0 + nt * 16 + l15;
            #pragma unroll
            for (int rg = 0; rg < 4; ++rg) {
                int co = mt * 16 + q * 4 + rg;
                out[(((size_t)b * DIM + co) * HH + h) * WW + wcol] = acc[mt][nt][rg] + biasr[mt][rg];
            }
        }
    }
}

extern "C" void kernel_launch(void* const* d_in, const int* in_sizes, int n_in,
                              void* d_out, int out_size, void* d_ws, size_t ws_size,
                              hipStream_t stream) {
    const float* x   = (const float*)d_in[0];
    const float* att = (const float*)d_in[1];
    const float* wgt = (const float*)d_in[2];
    const float* bia = (const float*)d_in[3];
    float* out = (float*)d_out;

    unsigned short* wmix = (unsigned short*)d_ws;            // 2,359,296 B
    float* bmix = (float*)((char*)d_ws + 2359296);           //     8,192 B

    mix_weights<<<512, 256, 0, stream>>>(wgt, att, wmix);
    mix_bias<<<8, 256, 0, stream>>>(bia, att, bmix);
    conv_mfma<<<2048, 256, 0, stream>>>(x, wmix, bmix, out);
}